// Round 4
// baseline (237.684 us; speedup 1.0000x reference)
//
#include <hip/hip_runtime.h>

#define CODEBOOK 1024
#define NGROUPS  8
#define CPG      128
#define Bn 32
#define Cn 256
#define Hn 32
#define Wn 32

#define ZQ_OFF   0
#define LOSS_OFF (Bn*Cn*Hn*Wn)      /* 8388608 */
#define IDX_OFF  (LOSS_OFF + 3)     /* 8388611 */

// ------------------------------------------------ A: fused prologue
// codebook = emb @ proj^T (sequential-k FMA chain, k ascending, one chain per
// output -- EXACT order of the validated round-2/3 kernels), plus per-code
// |c|^2 with the EXACT float4 + shfl_down(32..1) reduction of the old
// norm_kernel, plus lacc/counter init. proj is transposed through LDS
// (padded +1 -> conflict-free) instead of a separate transpose dispatch.
#define KT 32
__global__ __launch_bounds__(256) void codebook_fused(const float* __restrict__ emb,
                                                      const float* __restrict__ proj,
                                                      float* __restrict__ cb,
                                                      float* __restrict__ norms,
                                                      double* __restrict__ lacc,
                                                      int* __restrict__ counter) {
    __shared__ float emb4[4][Cn];
    __shared__ float pl[KT][Cn + 1];    // pl[k_local][j] = proj[j][k0+k_local]
    const int t  = threadIdx.x;
    const int i0 = blockIdx.x * 4;
    if (blockIdx.x == 0 && t == 0) { lacc[0] = 0.0; counter[0] = 0; }
#pragma unroll
    for (int m = 0; m < 4; ++m) {
        int id = t + m * 256;           // 0..1023
        int ci = id >> 8, k = id & 255;
        emb4[ci][k] = emb[(size_t)(i0 + ci) * Cn + k];
    }
    float acc[4] = {0.f, 0.f, 0.f, 0.f};
    for (int kc = 0; kc < Cn / KT; ++kc) {
        const int k0 = kc * KT;
        __syncthreads();                // previous pl tile fully consumed
#pragma unroll
        for (int m = 0; m < 8; ++m) {
            int id  = t + m * 256;      // 0..2047
            int row = id >> 3, q = id & 7;
            float4 v = *(const float4*)(proj + (size_t)row * Cn + k0 + q * 4);
            pl[q * 4 + 0][row] = v.x;
            pl[q * 4 + 1][row] = v.y;
            pl[q * 4 + 2][row] = v.z;
            pl[q * 4 + 3][row] = v.w;
        }
        __syncthreads();
        for (int kl = 0; kl < KT; ++kl) {
            float pj = pl[kl][t];       // stride-1, conflict-free
#pragma unroll
            for (int ci = 0; ci < 4; ++ci)
                acc[ci] = __builtin_fmaf(emb4[ci][k0 + kl], pj, acc[ci]);
        }
    }
    __syncthreads();
    float (*cbrow)[Cn] = (float (*)[Cn])&pl[0][0];   // reuse LDS (4 KB)
#pragma unroll
    for (int ci = 0; ci < 4; ++ci) {
        cb[(size_t)(i0 + ci) * Cn + t] = acc[ci];
        cbrow[ci][t] = acc[ci];
    }
    __syncthreads();
    if (t < 64) {
#pragma unroll
        for (int ci = 0; ci < 4; ++ci) {
            float4 v = ((const float4*)&cbrow[ci][0])[t];
            float s = v.x*v.x + v.y*v.y + v.z*v.z + v.w*v.w;
#pragma unroll
            for (int off = 32; off > 0; off >>= 1) s += __shfl_down(s, off);
            if (t == 0) norms[i0 + ci] = s;
        }
    }
}

// ------------------------------------------------------------- B: main VQ
// Block = (b, 16-row h tile, group g): 64 tokens x 128 codes x K=256.
// Thread tile: 4 tokens x 8 codes, sequential-k FMA accumulation (exact chain
// preserved from validated rounds). This round: T14 async-stage split --
// next kc's global loads issue into registers during compute; LDS writes
// happen after the barrier. Same values, same order, hidden latency.
__global__ __launch_bounds__(256) void vq_main(const float* __restrict__ z,
                                               const float* __restrict__ cb,
                                               const float* __restrict__ norms,
                                               float* __restrict__ out,
                                               double* __restrict__ lacc,
                                               int* __restrict__ counter) {
    __shared__ float ztile[64][64];   // [kk][tok]
    __shared__ float cbt[128][64];    // [ci][16B-slot swizzled: kq ^ (ci>>3)]
    __shared__ float zfin[64];
    __shared__ float red_d[64][16];
    __shared__ int   red_c[64][16];
    __shared__ int   bestidx[64];

    const int t   = threadIdx.x;
    // XCD sibling swizzle (validated r3): g-siblings of a (b,ht) pair land on
    // the same XCD -> z slab (512KB) L2-resident, FETCH 264->39MB.
    const int bid = blockIdx.x;
    const int r   = bid & 7;
    const int q   = bid >> 3;
    const int g   = q & 7;
    const int s   = ((q >> 3) << 3) | r;
    const int ht  = s & 1;
    const int b   = s >> 1;
    const int h0  = ht * 16;
    const int w0  = g * 4;

    const float* zb  = z  + (size_t)b * (Cn * Hn * Wn);
    const float* cbg = cb + (size_t)g * CPG * Cn;

    const int tok0  = (t & 15) * 4;
    const int code0 = (t >> 4) * 8;

    float acc[4][8];
#pragma unroll
    for (int rr2 = 0; rr2 < 4; ++rr2)
#pragma unroll
        for (int c = 0; c < 8; ++c) acc[rr2][c] = 0.f;

    float zr[16];                     // numpy pairwise partials (lanes t<64)
#pragma unroll
    for (int p = 0; p < 16; ++p) zr[p] = 0.f;

    // prefetch-register staging indices
    int z_kk[4], z_i[4], c_ci[8], c_kq[8];
#pragma unroll
    for (int m = 0; m < 4; ++m) { int id = t + m * 256; z_kk[m] = id >> 4; z_i[m] = id & 15; }
#pragma unroll
    for (int m = 0; m < 8; ++m) { int id = t + m * 256; c_ci[m] = id >> 4; c_kq[m] = id & 15; }

    float4 pz[4], pcb[8];
    auto issue_loads = [&](int k0) {
#pragma unroll
        for (int m = 0; m < 4; ++m)
            pz[m] = *(const float4*)(zb + (size_t)(k0 + z_kk[m]) * (Hn * Wn)
                                     + (h0 + z_i[m]) * Wn + w0);
#pragma unroll
        for (int m = 0; m < 8; ++m)
            pcb[m] = *(const float4*)(cbg + (size_t)c_ci[m] * Cn + k0 + c_kq[m] * 4);
    };

    issue_loads(0);
    for (int kc = 0; kc < 4; ++kc) {
        const int k0 = kc * 64;
        if (kc) __syncthreads();          // previous tile fully consumed
#pragma unroll
        for (int m = 0; m < 4; ++m)
            *(float4*)&ztile[z_kk[m]][z_i[m] * 4] = pz[m];
#pragma unroll
        for (int m = 0; m < 8; ++m)
            ((float4*)&cbt[c_ci[m]][0])[c_kq[m] ^ (c_ci[m] >> 3)] = pcb[m];
        __syncthreads();                  // tile ready
        if (kc < 3) issue_loads(k0 + 64); // in flight during compute below

        // |z|^2 partials: replicate numpy pairwise (8-acc stride-8, two halves).
        if (t < 64) {
#pragma clang fp contract(off)
            {
                const int base8 = (kc >> 1) * 8;
                for (int kk = 0; kk < 64; ++kk) {
                    float v  = ztile[kk][t];
                    float sq = v * v;             // rounded mul (no fma)
                    zr[base8 + (kk & 7)] += sq;   // rounded add
                }
            }
        }

        // register-tile GEMM: sequential k (chunks ascending, u ascending)
        for (int kb = 0; kb < 16; ++kb) {
            const int kk = kb * 4;
            float4 zt[4];
#pragma unroll
            for (int u = 0; u < 4; ++u)
                zt[u] = *(const float4*)&ztile[kk + u][tok0];
            float4 cf[8];
#pragma unroll
            for (int c = 0; c < 8; ++c)
                cf[c] = ((const float4*)&cbt[code0 + c][0])[kb ^ ((code0 + c) >> 3)];
#pragma unroll
            for (int u = 0; u < 4; ++u) {
                const float zu[4] = {
                    zt[u].x, zt[u].y, zt[u].z, zt[u].w };
                const float cu[8] = {
                    ((const float*)&cf[0])[u], ((const float*)&cf[1])[u],
                    ((const float*)&cf[2])[u], ((const float*)&cf[3])[u],
                    ((const float*)&cf[4])[u], ((const float*)&cf[5])[u],
                    ((const float*)&cf[6])[u], ((const float*)&cf[7])[u] };
#pragma unroll
                for (int rr3 = 0; rr3 < 4; ++rr3)
#pragma unroll
                    for (int c = 0; c < 8; ++c)
                        acc[rr3][c] = __builtin_fmaf(zu[rr3], cu[c], acc[rr3][c]);
            }
        }
    }

    // finalize |z|^2 with numpy's pairwise combination
    if (t < 64) {
#pragma clang fp contract(off)
        {
            float zh0 = ((zr[0] + zr[1]) + (zr[2] + zr[3]))
                      + ((zr[4] + zr[5]) + (zr[6] + zr[7]));
            float zh1 = ((zr[8] + zr[9]) + (zr[10] + zr[11]))
                      + ((zr[12] + zr[13]) + (zr[14] + zr[15]));
            zfin[t] = zh0 + zh1;
        }
    }
    __syncthreads();

    // per-thread argmin over its 8 codes (ascending -> first-min)
    float nv[8];
    *(float4*)&nv[0] = *(const float4*)(norms + g * CPG + code0);
    *(float4*)&nv[4] = *(const float4*)(norms + g * CPG + code0 + 4);
#pragma unroll
    for (int rr4 = 0; rr4 < 4; ++rr4) {
        float zv = zfin[tok0 + rr4];
        float bd = __builtin_inff();
        int   bc = 0;
#pragma unroll
        for (int c = 0; c < 8; ++c) {
            float ss = zv + nv[c];                // fl(Z + C_i)
            float d  = ss - 2.0f * acc[rr4][c];   // fl(S - 2T), 2T exact
            if (d < bd) { bd = d; bc = code0 + c; }
        }
        red_d[tok0 + rr4][t >> 4] = bd;
        red_c[tok0 + rr4][t >> 4] = bc;
    }
    __syncthreads();

    // cross-thread argmin, ascending code groups -> global first-min
    if (t < 64) {
        float bd = red_d[t][0];
        int   bc = red_c[t][0];
        for (int p = 1; p < 16; ++p) {
            float d = red_d[t][p];
            if (d < bd) { bd = d; bc = red_c[t][p]; }
        }
        int gidx = g * CPG + bc;
        bestidx[t] = gidx;
        int h = h0 + (t >> 2), w = w0 + (t & 3);
        out[IDX_OFF + b * (Hn * Wn) + h * Wn + w] = (float)gidx;
    }
    __syncthreads();

    // zq write (NCHW, float4 along w) + fused loss accumulation
    float lsum = 0.f;
    const size_t zbase = (size_t)b * (Cn * Hn * Wn);
#pragma unroll
    for (int m = 0; m < 16; ++m) {
        int id = t + m * 256;                     // 0..4095
        int c = id >> 4, i = id & 15;
        size_t off = zbase + (size_t)c * (Hn * Wn) + (h0 + i) * Wn + w0;
        float4 zv = *(const float4*)(z + off);
        float q0 = cb[(size_t)bestidx[i * 4 + 0] * Cn + c];
        float q1 = cb[(size_t)bestidx[i * 4 + 1] * Cn + c];
        float q2 = cb[(size_t)bestidx[i * 4 + 2] * Cn + c];
        float q3 = cb[(size_t)bestidx[i * 4 + 3] * Cn + c];
        float4 o; o.x = q0; o.y = q1; o.z = q2; o.w = q3;
        *(float4*)(out + ZQ_OFF + off) = o;
        float d0 = q0 - zv.x, d1 = q1 - zv.y, d2 = q2 - zv.z, d3 = q3 - zv.w;
        lsum = __builtin_fmaf(d0, d0, lsum);
        lsum = __builtin_fmaf(d1, d1, lsum);
        lsum = __builtin_fmaf(d2, d2, lsum);
        lsum = __builtin_fmaf(d3, d3, lsum);
    }
    __syncthreads();
    float* rr = &red_d[0][0];                     // reuse as float[256]
    rr[t] = lsum;
    __syncthreads();
    for (int s2 = 128; s2 > 0; s2 >>= 1) {
        if (t < s2) rr[t] += rr[t + s2];
        __syncthreads();
    }
    // fused finalize: last block to arrive writes the 3 loss scalars
    if (t == 0) {
        atomicAdd(lacc, (double)rr[0]);           // device-scope
        __threadfence();
        int done = atomicAdd(counter, 1);
        if (done == (int)gridDim.x - 1) {
            double tot = atomicAdd(lacc, 0.0);    // coherent read-back
            float M    = (float)(tot / (double)(Bn * Cn * Hn * Wn));
            float comm = 0.25f * M;
            out[LOSS_OFF + 0] = comm + M;   // loss
            out[LOSS_OFF + 1] = comm;       // commitment_loss
            out[LOSS_OFF + 2] = M;          // codebook_loss
        }
    }
}

extern "C" void kernel_launch(void* const* d_in, const int* in_sizes, int n_in,
                              void* d_out, int out_size, void* d_ws, size_t ws_size,
                              hipStream_t stream) {
    (void)in_sizes; (void)n_in; (void)out_size; (void)ws_size;
    const float* z    = (const float*)d_in[0];
    const float* emb  = (const float*)d_in[1];
    const float* proj = (const float*)d_in[2];
    float* out = (float*)d_out;

    char*   ws      = (char*)d_ws;
    float*  cb      = (float*)ws;                          // 1 MB
    float*  norms   = (float*)(ws + 1048576);              // 4 KB
    double* lacc    = (double*)(ws + 1048576 + 4096);      // 8 B
    int*    counter = (int*)(ws + 1048576 + 4096 + 8);     // 4 B

    codebook_fused<<<CODEBOOK/4, 256, 0, stream>>>(emb, proj, cb, norms, lacc, counter);
    vq_main       <<<Bn*2*NGROUPS, 256, 0, stream>>>(z, cb, norms, out, lacc, counter);
}

// Round 5
// 233.990 us; speedup vs baseline: 1.0158x; 1.0158x over previous
//
#include <hip/hip_runtime.h>

#define CODEBOOK 1024
#define NGROUPS  8
#define CPG      128
#define Bn 32
#define Cn 256
#define Hn 32
#define Wn 32

#define ZQ_OFF   0
#define LOSS_OFF (Bn*Cn*Hn*Wn)      /* 8388608 */
#define IDX_OFF  (LOSS_OFF + 3)     /* 8388611 */

// ------------------------------------------------ A: codebook (direct)
// cb[i][j] = sum_k emb[i][k]*proj[j][k], k-ascending single-accumulator FMA
// chain per output -- bit-identical to the validated r2/r3 chain (which used
// projT[k][j] == proj[j][k]). proj rows are contiguous in k, so each lane
// streams 4 rows with float4 loads; emb row broadcast from LDS.
__global__ __launch_bounds__(64) void prologue_cb(const float* __restrict__ emb,
                                                  const float* __restrict__ proj,
                                                  float* __restrict__ cb,
                                                  double* __restrict__ lacc,
                                                  int* __restrict__ counter) {
    __shared__ float embrow[Cn];
    const int l = threadIdx.x;        // 0..63
    const int i = blockIdx.x;         // codebook row 0..1023
    if (i == 0 && l == 0) { lacc[0] = 0.0; counter[0] = 0; }
    *(float4*)&embrow[l * 4] = *(const float4*)(emb + (size_t)i * Cn + l * 4);
    __syncthreads();
    const float* p0 = proj + (size_t)(4 * l + 0) * Cn;
    const float* p1 = proj + (size_t)(4 * l + 1) * Cn;
    const float* p2 = proj + (size_t)(4 * l + 2) * Cn;
    const float* p3 = proj + (size_t)(4 * l + 3) * Cn;
    float a0 = 0.f, a1 = 0.f, a2 = 0.f, a3 = 0.f;
    for (int kq = 0; kq < 64; ++kq) {
        float4 e  = ((const float4*)embrow)[kq];      // same-addr broadcast
        float4 q0 = *(const float4*)(p0 + kq * 4);
        float4 q1 = *(const float4*)(p1 + kq * 4);
        float4 q2 = *(const float4*)(p2 + kq * 4);
        float4 q3 = *(const float4*)(p3 + kq * 4);
        a0 = __builtin_fmaf(e.x, q0.x, a0); a0 = __builtin_fmaf(e.y, q0.y, a0);
        a0 = __builtin_fmaf(e.z, q0.z, a0); a0 = __builtin_fmaf(e.w, q0.w, a0);
        a1 = __builtin_fmaf(e.x, q1.x, a1); a1 = __builtin_fmaf(e.y, q1.y, a1);
        a1 = __builtin_fmaf(e.z, q1.z, a1); a1 = __builtin_fmaf(e.w, q1.w, a1);
        a2 = __builtin_fmaf(e.x, q2.x, a2); a2 = __builtin_fmaf(e.y, q2.y, a2);
        a2 = __builtin_fmaf(e.z, q2.z, a2); a2 = __builtin_fmaf(e.w, q2.w, a2);
        a3 = __builtin_fmaf(e.x, q3.x, a3); a3 = __builtin_fmaf(e.y, q3.y, a3);
        a3 = __builtin_fmaf(e.z, q3.z, a3); a3 = __builtin_fmaf(e.w, q3.w, a3);
    }
    float4 o; o.x = a0; o.y = a1; o.z = a2; o.w = a3;
    *(float4*)(cb + (size_t)i * Cn + 4 * l) = o;
}

// --------------------------------------------------- A2: per-code |c|^2
// VERBATIM from the validated rounds (reads identical cb bits from global ->
// identical norms bits). DO NOT restructure.
__global__ __launch_bounds__(64) void norm_kernel(const float* __restrict__ cb,
                                                  float* __restrict__ norms) {
    int i = blockIdx.x, l = threadIdx.x;
    float4 v = *(const float4*)(cb + (size_t)i * Cn + l * 4);
    float s = v.x*v.x + v.y*v.y + v.z*v.z + v.w*v.w;
#pragma unroll
    for (int off = 32; off > 0; off >>= 1) s += __shfl_down(s, off);
    if (l == 0) norms[i] = s;
}

// ------------------------------------------------------------- B: main VQ
// Block = (b, 16-row h tile, group g): 64 tokens x 128 codes x K=256.
// Thread tile: 4 tokens x 8 codes, sequential-k FMA accumulation (exact
// chains of the validated rounds). Round-5: T14 prefetch with VGPR headroom
// (__launch_bounds__(256,2) -- r4's spill fix) + |z|^2 spread over 4
// threads/token with a bit-exact shfl_xor pairwise combine.
__global__ __launch_bounds__(256, 2) void vq_main(const float* __restrict__ z,
                                                  const float* __restrict__ cb,
                                                  const float* __restrict__ norms,
                                                  float* __restrict__ out,
                                                  double* __restrict__ lacc,
                                                  int* __restrict__ counter) {
    __shared__ float ztile[64][64];   // [kk][tok]
    __shared__ float cbt[128][64];    // [ci][16B-slot swizzled: kq ^ (ci>>3)]
    __shared__ float zfin[64];
    __shared__ float red_d[64][16];
    __shared__ int   red_c[64][16];
    __shared__ int   bestidx[64];

    const int t   = threadIdx.x;
    // XCD sibling swizzle (validated r3): g-siblings of a (b,ht) pair land on
    // the same XCD -> z slab L2-resident (FETCH 264->39MB).
    const int bid = blockIdx.x;
    const int r   = bid & 7;
    const int q   = bid >> 3;
    const int g   = q & 7;
    const int s   = ((q >> 3) << 3) | r;
    const int ht  = s & 1;
    const int b   = s >> 1;
    const int h0  = ht * 16;
    const int w0  = g * 4;

    const float* zb  = z  + (size_t)b * (Cn * Hn * Wn);
    const float* cbg = cb + (size_t)g * CPG * Cn;

    const int tok0  = (t & 15) * 4;
    const int code0 = (t >> 4) * 8;
    const int tok   = t >> 2;         // |z|^2 ownership: token, sub-lane
    const int a     = t & 3;

    float acc[4][8];
#pragma unroll
    for (int rr2 = 0; rr2 < 4; ++rr2)
#pragma unroll
        for (int c = 0; c < 8; ++c) acc[rr2][c] = 0.f;

    // numpy-pairwise |z|^2 partial accumulators: thread a owns accumulator
    // indices {a, a+4} of each half (k-order within each preserved).
    float zr00 = 0.f, zr01 = 0.f, zr10 = 0.f, zr11 = 0.f;

    // prefetch-register staging indices
    int z_kk[4], z_i[4], c_ci[8], c_kq[8];
#pragma unroll
    for (int m = 0; m < 4; ++m) { int id = t + m * 256; z_kk[m] = id >> 4; z_i[m] = id & 15; }
#pragma unroll
    for (int m = 0; m < 8; ++m) { int id = t + m * 256; c_ci[m] = id >> 4; c_kq[m] = id & 15; }

    float4 pz[4], pcb[8];
    auto issue_loads = [&](int k0) {
#pragma unroll
        for (int m = 0; m < 4; ++m)
            pz[m] = *(const float4*)(zb + (size_t)(k0 + z_kk[m]) * (Hn * Wn)
                                     + (h0 + z_i[m]) * Wn + w0);
#pragma unroll
        for (int m = 0; m < 8; ++m)
            pcb[m] = *(const float4*)(cbg + (size_t)c_ci[m] * Cn + k0 + c_kq[m] * 4);
    };

    issue_loads(0);
    for (int kc = 0; kc < 4; ++kc) {
        const int k0 = kc * 64;
        if (kc) __syncthreads();          // previous tile fully consumed
#pragma unroll
        for (int m = 0; m < 4; ++m)
            *(float4*)&ztile[z_kk[m]][z_i[m] * 4] = pz[m];
#pragma unroll
        for (int m = 0; m < 8; ++m)
            ((float4*)&cbt[c_ci[m]][0])[c_kq[m] ^ (c_ci[m] >> 3)] = pcb[m];
        __syncthreads();                  // tile ready
        if (kc < 3) issue_loads(k0 + 64); // in flight during compute below

        // |z|^2 partials: numpy pairwise, 4 threads/token. kk = 4*kq + a
        // => accumulator (kk&7) alternates a (kq even) / a+4 (kq odd);
        // each accumulator sees its kk's in ascending order, as before.
        {
#pragma clang fp contract(off)
            if (kc < 2) {
#pragma unroll
                for (int kq = 0; kq < 16; ++kq) {
                    float v  = ztile[kq * 4 + a][tok];
                    float sq = v * v;
                    if (kq & 1) zr01 += sq; else zr00 += sq;
                }
            } else {
#pragma unroll
                for (int kq = 0; kq < 16; ++kq) {
                    float v  = ztile[kq * 4 + a][tok];
                    float sq = v * v;
                    if (kq & 1) zr11 += sq; else zr10 += sq;
                }
            }
        }

        // register-tile GEMM: sequential k (chunks ascending, u ascending)
        for (int kb = 0; kb < 16; ++kb) {
            const int kk = kb * 4;
            float4 zt[4];
#pragma unroll
            for (int u = 0; u < 4; ++u)
                zt[u] = *(const float4*)&ztile[kk + u][tok0];
            float4 cf[8];
#pragma unroll
            for (int c = 0; c < 8; ++c)
                cf[c] = ((const float4*)&cbt[code0 + c][0])[kb ^ ((code0 + c) >> 3)];
#pragma unroll
            for (int u = 0; u < 4; ++u) {
                const float zu[4] = {
                    zt[u].x, zt[u].y, zt[u].z, zt[u].w };
                const float cu[8] = {
                    ((const float*)&cf[0])[u], ((const float*)&cf[1])[u],
                    ((const float*)&cf[2])[u], ((const float*)&cf[3])[u],
                    ((const float*)&cf[4])[u], ((const float*)&cf[5])[u],
                    ((const float*)&cf[6])[u], ((const float*)&cf[7])[u] };
#pragma unroll
                for (int rr3 = 0; rr3 < 4; ++rr3)
#pragma unroll
                    for (int c = 0; c < 8; ++c)
                        acc[rr3][c] = __builtin_fmaf(zu[rr3], cu[c], acc[rr3][c]);
            }
        }
    }

    // |z|^2 combine: exact numpy tree ((r0+r1)+(r2+r3)) + ((r4+r5)+(r6+r7))
    // per half, then zh0+zh1. Lane a=0 of each 4-lane group holds the result.
    {
#pragma clang fp contract(off)
        float s1 = zr00 + __shfl_xor(zr00, 1);
        float s2 = s1   + __shfl_xor(s1, 2);    // a=0: (r0+r1)+(r2+r3)
        float q1 = zr01 + __shfl_xor(zr01, 1);
        float q2 = q1   + __shfl_xor(q1, 2);    // a=0: (r4+r5)+(r6+r7)
        float zh0 = s2 + q2;
        float t1 = zr10 + __shfl_xor(zr10, 1);
        float t2 = t1   + __shfl_xor(t1, 2);
        float u1 = zr11 + __shfl_xor(zr11, 1);
        float u2 = u1   + __shfl_xor(u1, 2);
        float zh1 = t2 + u2;
        if (a == 0) zfin[tok] = zh0 + zh1;
    }
    __syncthreads();

    // per-thread argmin over its 8 codes (ascending -> first-min)
    float nv[8];
    *(float4*)&nv[0] = *(const float4*)(norms + g * CPG + code0);
    *(float4*)&nv[4] = *(const float4*)(norms + g * CPG + code0 + 4);
#pragma unroll
    for (int rr4 = 0; rr4 < 4; ++rr4) {
        float zv = zfin[tok0 + rr4];
        float bd = __builtin_inff();
        int   bc = 0;
#pragma unroll
        for (int c = 0; c < 8; ++c) {
            float ss = zv + nv[c];                // fl(Z + C_i)
            float d  = ss - 2.0f * acc[rr4][c];   // fl(S - 2T), 2T exact
            if (d < bd) { bd = d; bc = code0 + c; }
        }
        red_d[tok0 + rr4][t >> 4] = bd;
        red_c[tok0 + rr4][t >> 4] = bc;
    }
    __syncthreads();

    // cross-thread argmin, ascending code groups -> global first-min
    if (t < 64) {
        float bd = red_d[t][0];
        int   bc = red_c[t][0];
        for (int p = 1; p < 16; ++p) {
            float d = red_d[t][p];
            if (d < bd) { bd = d; bc = red_c[t][p]; }
        }
        int gidx = g * CPG + bc;
        bestidx[t] = gidx;
        int h = h0 + (t >> 2), w = w0 + (t & 3);
        out[IDX_OFF + b * (Hn * Wn) + h * Wn + w] = (float)gidx;
    }
    __syncthreads();

    // zq write (NCHW, float4 along w) + fused loss accumulation
    float lsum = 0.f;
    const size_t zbase = (size_t)b * (Cn * Hn * Wn);
#pragma unroll
    for (int m = 0; m < 16; ++m) {
        int id = t + m * 256;                     // 0..4095
        int c = id >> 4, i = id & 15;
        size_t off = zbase + (size_t)c * (Hn * Wn) + (h0 + i) * Wn + w0;
        float4 zv = *(const float4*)(z + off);
        float q0 = cb[(size_t)bestidx[i * 4 + 0] * Cn + c];
        float q1 = cb[(size_t)bestidx[i * 4 + 1] * Cn + c];
        float q2 = cb[(size_t)bestidx[i * 4 + 2] * Cn + c];
        float q3 = cb[(size_t)bestidx[i * 4 + 3] * Cn + c];
        float4 o; o.x = q0; o.y = q1; o.z = q2; o.w = q3;
        *(float4*)(out + ZQ_OFF + off) = o;
        float d0 = q0 - zv.x, d1 = q1 - zv.y, d2 = q2 - zv.z, d3 = q3 - zv.w;
        lsum = __builtin_fmaf(d0, d0, lsum);
        lsum = __builtin_fmaf(d1, d1, lsum);
        lsum = __builtin_fmaf(d2, d2, lsum);
        lsum = __builtin_fmaf(d3, d3, lsum);
    }
    __syncthreads();
    float* rr = &red_d[0][0];                     // reuse as float[256]
    rr[t] = lsum;
    __syncthreads();
    for (int s2 = 128; s2 > 0; s2 >>= 1) {
        if (t < s2) rr[t] += rr[t + s2];
        __syncthreads();
    }
    // fused finalize: last block to arrive writes the 3 loss scalars
    if (t == 0) {
        atomicAdd(lacc, (double)rr[0]);           // device-scope
        __threadfence();
        int done = atomicAdd(counter, 1);
        if (done == (int)gridDim.x - 1) {
            double tot = atomicAdd(lacc, 0.0);    // coherent read-back
            float M    = (float)(tot / (double)(Bn * Cn * Hn * Wn));
            float comm = 0.25f * M;
            out[LOSS_OFF + 0] = comm + M;   // loss
            out[LOSS_OFF + 1] = comm;       // commitment_loss
            out[LOSS_OFF + 2] = M;          // codebook_loss
        }
    }
}

extern "C" void kernel_launch(void* const* d_in, const int* in_sizes, int n_in,
                              void* d_out, int out_size, void* d_ws, size_t ws_size,
                              hipStream_t stream) {
    (void)in_sizes; (void)n_in; (void)out_size; (void)ws_size;
    const float* z    = (const float*)d_in[0];
    const float* emb  = (const float*)d_in[1];
    const float* proj = (const float*)d_in[2];
    float* out = (float*)d_out;

    char*   ws      = (char*)d_ws;
    float*  cb      = (float*)ws;                          // 1 MB
    float*  norms   = (float*)(ws + 1048576);              // 4 KB
    double* lacc    = (double*)(ws + 1048576 + 4096);      // 8 B
    int*    counter = (int*)(ws + 1048576 + 4096 + 8);     // 4 B

    prologue_cb<<<CODEBOOK, 64, 0, stream>>>(emb, proj, cb, lacc, counter);
    norm_kernel<<<CODEBOOK, 64, 0, stream>>>(cb, norms);
    vq_main    <<<Bn*2*NGROUPS, 256, 0, stream>>>(z, cb, norms, out, lacc, counter);
}

// Round 6
// 205.113 us; speedup vs baseline: 1.1588x; 1.1408x over previous
//
#include <hip/hip_runtime.h>

#define CODEBOOK 1024
#define NGROUPS  8
#define CPG      128
#define Bn 32
#define Cn 256
#define Hn 32
#define Wn 32

#define ZQ_OFF   0
#define LOSS_OFF (Bn*Cn*Hn*Wn)      /* 8388608 */
#define IDX_OFF  (LOSS_OFF + 3)     /* 8388611 */

// ------------------------------------------------ A: codebook + norms (fused)
// cb[i][j] = sum_k emb[i][k]*proj[j][k], k-ascending single-accumulator FMA
// chain per output -- bit-identical to the validated chain. Lane l of block i
// ends holding cb[i][4l:4l+4] == the exact float4 the old norm_kernel's lane l
// would re-load, so the norm reduction (same op order: ((xx+yy)+zz)+ww then
// shfl_down 32..1) is fused here at zero numeric risk.
__global__ __launch_bounds__(64) void prologue_cb(const float* __restrict__ emb,
                                                  const float* __restrict__ proj,
                                                  float* __restrict__ cb,
                                                  float* __restrict__ norms,
                                                  double* __restrict__ lacc,
                                                  int* __restrict__ counter) {
    __shared__ float embrow[Cn];
    const int l = threadIdx.x;        // 0..63
    const int i = blockIdx.x;         // codebook row 0..1023
    if (i == 0 && l == 0) { lacc[0] = 0.0; counter[0] = 0; }
    *(float4*)&embrow[l * 4] = *(const float4*)(emb + (size_t)i * Cn + l * 4);
    __syncthreads();
    const float* p0 = proj + (size_t)(4 * l + 0) * Cn;
    const float* p1 = proj + (size_t)(4 * l + 1) * Cn;
    const float* p2 = proj + (size_t)(4 * l + 2) * Cn;
    const float* p3 = proj + (size_t)(4 * l + 3) * Cn;
    float a0 = 0.f, a1 = 0.f, a2 = 0.f, a3 = 0.f;
    for (int kq = 0; kq < 64; ++kq) {
        float4 e  = ((const float4*)embrow)[kq];      // same-addr broadcast
        float4 q0 = *(const float4*)(p0 + kq * 4);
        float4 q1 = *(const float4*)(p1 + kq * 4);
        float4 q2 = *(const float4*)(p2 + kq * 4);
        float4 q3 = *(const float4*)(p3 + kq * 4);
        a0 = __builtin_fmaf(e.x, q0.x, a0); a0 = __builtin_fmaf(e.y, q0.y, a0);
        a0 = __builtin_fmaf(e.z, q0.z, a0); a0 = __builtin_fmaf(e.w, q0.w, a0);
        a1 = __builtin_fmaf(e.x, q1.x, a1); a1 = __builtin_fmaf(e.y, q1.y, a1);
        a1 = __builtin_fmaf(e.z, q1.z, a1); a1 = __builtin_fmaf(e.w, q1.w, a1);
        a2 = __builtin_fmaf(e.x, q2.x, a2); a2 = __builtin_fmaf(e.y, q2.y, a2);
        a2 = __builtin_fmaf(e.z, q2.z, a2); a2 = __builtin_fmaf(e.w, q2.w, a2);
        a3 = __builtin_fmaf(e.x, q3.x, a3); a3 = __builtin_fmaf(e.y, q3.y, a3);
        a3 = __builtin_fmaf(e.z, q3.z, a3); a3 = __builtin_fmaf(e.w, q3.w, a3);
    }
    float4 o; o.x = a0; o.y = a1; o.z = a2; o.w = a3;
    *(float4*)(cb + (size_t)i * Cn + 4 * l) = o;
    // fused |c|^2 -- VERBATIM op order of the validated norm_kernel
    float s = o.x*o.x + o.y*o.y + o.z*o.z + o.w*o.w;
#pragma unroll
    for (int off = 32; off > 0; off >>= 1) s += __shfl_down(s, off);
    if (l == 0) norms[i] = s;
}

// ------------------------------------------------------------- B: main VQ
// Block = (b, 16-row h tile, group g): 64 tokens x 128 codes x K=256.
// Thread tile: 4 tokens x 8 codes, sequential-k FMA accumulation (exact
// chains of the validated rounds). Round-6: prefetch via NAMED SCALAR float4s
// (no arrays, no lambda -> no alloca -> AMDGPUPromoteAlloca can't demote to
// LDS/scratch, which is what r4/r5's counters showed: LDS +16384 = pz,
// WRITE_SIZE 103MB = pcb in scratch).
__global__ __launch_bounds__(256, 2) void vq_main(const float* __restrict__ z,
                                                  const float* __restrict__ cb,
                                                  const float* __restrict__ norms,
                                                  float* __restrict__ out,
                                                  double* __restrict__ lacc,
                                                  int* __restrict__ counter) {
    __shared__ float ztile[64][64];   // [kk][tok]
    __shared__ float cbt[128][64];    // [ci][16B-slot swizzled: kq ^ (ci>>3)]
    __shared__ float zfin[64];
    __shared__ float red_d[64][16];
    __shared__ int   red_c[64][16];
    __shared__ int   bestidx[64];

    const int t   = threadIdx.x;
    // XCD sibling swizzle (validated r3): g-siblings of a (b,ht) pair land on
    // the same XCD -> z slab L2-resident (FETCH 264->39MB).
    const int bid = blockIdx.x;
    const int r   = bid & 7;
    const int q   = bid >> 3;
    const int g   = q & 7;
    const int s   = ((q >> 3) << 3) | r;
    const int ht  = s & 1;
    const int b   = s >> 1;
    const int h0  = ht * 16;
    const int w0  = g * 4;

    const float* zb  = z  + (size_t)b * (Cn * Hn * Wn);
    const float* cbg = cb + (size_t)g * CPG * Cn;

    const int tok0  = (t & 15) * 4;
    const int code0 = (t >> 4) * 8;
    const int tok   = t >> 2;         // |z|^2 ownership: token, sub-lane
    const int a     = t & 3;

    // staging geometry: id = t + 256m => id&15 == t&15 (const), id>>4 == hi+16m
    const int lane15 = t & 15;
    const int hi     = t >> 4;                    // 0..15
    const int zoff   = (h0 + lane15) * Wn + w0;   // col offset in a k-plane
    const int coff   = lane15 * 4;                // k offset in a cb row

    float acc[4][8];
#pragma unroll
    for (int rr2 = 0; rr2 < 4; ++rr2)
#pragma unroll
        for (int c = 0; c < 8; ++c) acc[rr2][c] = 0.f;

    // numpy-pairwise |z|^2 partial accumulators (validated r5): thread a owns
    // accumulator indices {a, a+4} of each half, k-order preserved.
    float zr00 = 0.f, zr01 = 0.f, zr10 = 0.f, zr11 = 0.f;

    // prefetch registers -- named scalars, NOT arrays (see header comment)
    float4 pz0, pz1, pz2, pz3;
    float4 pc0, pc1, pc2, pc3, pc4, pc5, pc6, pc7;

#define ISSUE_LOADS(K0)                                                        \
    pz0 = *(const float4*)(zb + (size_t)((K0) + hi +  0) * (Hn*Wn) + zoff);    \
    pz1 = *(const float4*)(zb + (size_t)((K0) + hi + 16) * (Hn*Wn) + zoff);    \
    pz2 = *(const float4*)(zb + (size_t)((K0) + hi + 32) * (Hn*Wn) + zoff);    \
    pz3 = *(const float4*)(zb + (size_t)((K0) + hi + 48) * (Hn*Wn) + zoff);    \
    pc0 = *(const float4*)(cbg + (size_t)(hi +   0) * Cn + (K0) + coff);       \
    pc1 = *(const float4*)(cbg + (size_t)(hi +  16) * Cn + (K0) + coff);       \
    pc2 = *(const float4*)(cbg + (size_t)(hi +  32) * Cn + (K0) + coff);       \
    pc3 = *(const float4*)(cbg + (size_t)(hi +  48) * Cn + (K0) + coff);       \
    pc4 = *(const float4*)(cbg + (size_t)(hi +  64) * Cn + (K0) + coff);       \
    pc5 = *(const float4*)(cbg + (size_t)(hi +  80) * Cn + (K0) + coff);       \
    pc6 = *(const float4*)(cbg + (size_t)(hi +  96) * Cn + (K0) + coff);       \
    pc7 = *(const float4*)(cbg + (size_t)(hi + 112) * Cn + (K0) + coff);

#define STORE_LDS()                                                            \
    *(float4*)&ztile[hi +  0][lane15 * 4] = pz0;                               \
    *(float4*)&ztile[hi + 16][lane15 * 4] = pz1;                               \
    *(float4*)&ztile[hi + 32][lane15 * 4] = pz2;                               \
    *(float4*)&ztile[hi + 48][lane15 * 4] = pz3;                               \
    ((float4*)&cbt[hi +   0][0])[lane15 ^ ((hi +   0) >> 3)] = pc0;            \
    ((float4*)&cbt[hi +  16][0])[lane15 ^ ((hi +  16) >> 3)] = pc1;            \
    ((float4*)&cbt[hi +  32][0])[lane15 ^ ((hi +  32) >> 3)] = pc2;            \
    ((float4*)&cbt[hi +  48][0])[lane15 ^ ((hi +  48) >> 3)] = pc3;            \
    ((float4*)&cbt[hi +  64][0])[lane15 ^ ((hi +  64) >> 3)] = pc4;            \
    ((float4*)&cbt[hi +  80][0])[lane15 ^ ((hi +  80) >> 3)] = pc5;            \
    ((float4*)&cbt[hi +  96][0])[lane15 ^ ((hi +  96) >> 3)] = pc6;            \
    ((float4*)&cbt[hi + 112][0])[lane15 ^ ((hi + 112) >> 3)] = pc7;

    ISSUE_LOADS(0)
    for (int kc = 0; kc < 4; ++kc) {
        const int k0 = kc * 64;
        if (kc) __syncthreads();          // previous tile fully consumed
        STORE_LDS()
        __syncthreads();                  // tile ready
        if (kc < 3) { ISSUE_LOADS(k0 + 64) }  // in flight during compute

        // |z|^2 partials: numpy pairwise, 4 threads/token (validated r5).
        {
#pragma clang fp contract(off)
            if (kc < 2) {
#pragma unroll
                for (int kq = 0; kq < 16; ++kq) {
                    float v  = ztile[kq * 4 + a][tok];
                    float sq = v * v;
                    if (kq & 1) zr01 += sq; else zr00 += sq;
                }
            } else {
#pragma unroll
                for (int kq = 0; kq < 16; ++kq) {
                    float v  = ztile[kq * 4 + a][tok];
                    float sq = v * v;
                    if (kq & 1) zr11 += sq; else zr10 += sq;
                }
            }
        }

        // register-tile GEMM: sequential k (chunks ascending, u ascending)
        for (int kb = 0; kb < 16; ++kb) {
            const int kk = kb * 4;
            float4 zt[4];
#pragma unroll
            for (int u = 0; u < 4; ++u)
                zt[u] = *(const float4*)&ztile[kk + u][tok0];
            float4 cf[8];
#pragma unroll
            for (int c = 0; c < 8; ++c)
                cf[c] = ((const float4*)&cbt[code0 + c][0])[kb ^ ((code0 + c) >> 3)];
#pragma unroll
            for (int u = 0; u < 4; ++u) {
                const float zu[4] = {
                    zt[u].x, zt[u].y, zt[u].z, zt[u].w };
                const float cu[8] = {
                    ((const float*)&cf[0])[u], ((const float*)&cf[1])[u],
                    ((const float*)&cf[2])[u], ((const float*)&cf[3])[u],
                    ((const float*)&cf[4])[u], ((const float*)&cf[5])[u],
                    ((const float*)&cf[6])[u], ((const float*)&cf[7])[u] };
#pragma unroll
                for (int rr3 = 0; rr3 < 4; ++rr3)
#pragma unroll
                    for (int c = 0; c < 8; ++c)
                        acc[rr3][c] = __builtin_fmaf(zu[rr3], cu[c], acc[rr3][c]);
            }
        }
    }
#undef ISSUE_LOADS
#undef STORE_LDS

    // |z|^2 combine: exact numpy tree ((r0+r1)+(r2+r3)) + ((r4+r5)+(r6+r7))
    // per half, then zh0+zh1 (validated r5).
    {
#pragma clang fp contract(off)
        float s1 = zr00 + __shfl_xor(zr00, 1);
        float s2 = s1   + __shfl_xor(s1, 2);
        float q1 = zr01 + __shfl_xor(zr01, 1);
        float q2 = q1   + __shfl_xor(q1, 2);
        float zh0 = s2 + q2;
        float t1 = zr10 + __shfl_xor(zr10, 1);
        float t2 = t1   + __shfl_xor(t1, 2);
        float u1 = zr11 + __shfl_xor(zr11, 1);
        float u2 = u1   + __shfl_xor(u1, 2);
        float zh1 = t2 + u2;
        if (a == 0) zfin[tok] = zh0 + zh1;
    }
    __syncthreads();

    // per-thread argmin over its 8 codes (ascending -> first-min)
    float nv[8];
    *(float4*)&nv[0] = *(const float4*)(norms + g * CPG + code0);
    *(float4*)&nv[4] = *(const float4*)(norms + g * CPG + code0 + 4);
#pragma unroll
    for (int rr4 = 0; rr4 < 4; ++rr4) {
        float zv = zfin[tok0 + rr4];
        float bd = __builtin_inff();
        int   bc = 0;
#pragma unroll
        for (int c = 0; c < 8; ++c) {
            float ss = zv + nv[c];                // fl(Z + C_i)
            float d  = ss - 2.0f * acc[rr4][c];   // fl(S - 2T), 2T exact
            if (d < bd) { bd = d; bc = code0 + c; }
        }
        red_d[tok0 + rr4][t >> 4] = bd;
        red_c[tok0 + rr4][t >> 4] = bc;
    }
    __syncthreads();

    // cross-thread argmin, ascending code groups -> global first-min
    if (t < 64) {
        float bd = red_d[t][0];
        int   bc = red_c[t][0];
        for (int p = 1; p < 16; ++p) {
            float d = red_d[t][p];
            if (d < bd) { bd = d; bc = red_c[t][p]; }
        }
        int gidx = g * CPG + bc;
        bestidx[t] = gidx;
        int h = h0 + (t >> 2), w = w0 + (t & 3);
        out[IDX_OFF + b * (Hn * Wn) + h * Wn + w] = (float)gidx;
    }
    __syncthreads();

    // zq write (NCHW, float4 along w) + fused loss accumulation
    float lsum = 0.f;
    const size_t zbase = (size_t)b * (Cn * Hn * Wn);
#pragma unroll
    for (int m = 0; m < 16; ++m) {
        int id = t + m * 256;                     // 0..4095
        int c = id >> 4, i = id & 15;
        size_t off = zbase + (size_t)c * (Hn * Wn) + (h0 + i) * Wn + w0;
        float4 zv = *(const float4*)(z + off);
        float q0 = cb[(size_t)bestidx[i * 4 + 0] * Cn + c];
        float q1 = cb[(size_t)bestidx[i * 4 + 1] * Cn + c];
        float q2 = cb[(size_t)bestidx[i * 4 + 2] * Cn + c];
        float q3 = cb[(size_t)bestidx[i * 4 + 3] * Cn + c];
        float4 o; o.x = q0; o.y = q1; o.z = q2; o.w = q3;
        *(float4*)(out + ZQ_OFF + off) = o;
        float d0 = q0 - zv.x, d1 = q1 - zv.y, d2 = q2 - zv.z, d3 = q3 - zv.w;
        lsum = __builtin_fmaf(d0, d0, lsum);
        lsum = __builtin_fmaf(d1, d1, lsum);
        lsum = __builtin_fmaf(d2, d2, lsum);
        lsum = __builtin_fmaf(d3, d3, lsum);
    }
    __syncthreads();
    float* rr = &red_d[0][0];                     // reuse as float[256]
    rr[t] = lsum;
    __syncthreads();
    for (int s2 = 128; s2 > 0; s2 >>= 1) {
        if (t < s2) rr[t] += rr[t + s2];
        __syncthreads();
    }
    // fused finalize: last block to arrive writes the 3 loss scalars
    if (t == 0) {
        atomicAdd(lacc, (double)rr[0]);           // device-scope
        __threadfence();
        int done = atomicAdd(counter, 1);
        if (done == (int)gridDim.x - 1) {
            double tot = atomicAdd(lacc, 0.0);    // coherent read-back
            float M    = (float)(tot / (double)(Bn * Cn * Hn * Wn));
            float comm = 0.25f * M;
            out[LOSS_OFF + 0] = comm + M;   // loss
            out[LOSS_OFF + 1] = comm;       // commitment_loss
            out[LOSS_OFF + 2] = M;          // codebook_loss
        }
    }
}

extern "C" void kernel_launch(void* const* d_in, const int* in_sizes, int n_in,
                              void* d_out, int out_size, void* d_ws, size_t ws_size,
                              hipStream_t stream) {
    (void)in_sizes; (void)n_in; (void)out_size; (void)ws_size;
    const float* z    = (const float*)d_in[0];
    const float* emb  = (const float*)d_in[1];
    const float* proj = (const float*)d_in[2];
    float* out = (float*)d_out;

    char*   ws      = (char*)d_ws;
    float*  cb      = (float*)ws;                          // 1 MB
    float*  norms   = (float*)(ws + 1048576);              // 4 KB
    double* lacc    = (double*)(ws + 1048576 + 4096);      // 8 B
    int*    counter = (int*)(ws + 1048576 + 4096 + 8);     // 4 B

    prologue_cb<<<CODEBOOK, 64, 0, stream>>>(emb, proj, cb, norms, lacc, counter);
    vq_main    <<<Bn*2*NGROUPS, 256, 0, stream>>>(z, cb, norms, out, lacc, counter);
}